// Round 9
// baseline (813.456 us; speedup 1.0000x reference)
//
#include <hip/hip_runtime.h>
#include <hip/hip_bf16.h>

// ---- problem constants ----
#define D_MODEL   512
#define D_STATE   128
#define D_CONV    4
#define HEADDIM   64
#define NLAYERS   2
#define D_INNER   1024
#define NHEADS    16
#define CONV_DIM  1280          // D_INNER + 2*D_STATE
#define D_IN_PROJ 2320          // 2*D_INNER + 2*D_STATE + NHEADS
#define NPAD      2560          // D_IN_PROJ padded to 256
#define SEQ       64
#define BATCH     512
#define NTOK      (BATCH*SEQ)   // 32768
#define FC_HID    128
#define EPS       1e-5f

using bf16 = __hip_bfloat16;
typedef __bf16 bf16x8 __attribute__((ext_vector_type(8)));
typedef float  f32x4  __attribute__((ext_vector_type(4)));

__device__ __forceinline__ float b2f(bf16 v)  { return __bfloat162float(v); }
__device__ __forceinline__ bf16  f2b(float v) { return __float2bfloat16(v); }
__device__ __forceinline__ float bflo(unsigned u){ return __builtin_bit_cast(float, u << 16); }
__device__ __forceinline__ float bfhi(unsigned u){ return __builtin_bit_cast(float, u & 0xffff0000u); }

__device__ __forceinline__ void gl_lds16(const void* g, void* l) {
    __builtin_amdgcn_global_load_lds((const __attribute__((address_space(1))) void*)g,
                                     (__attribute__((address_space(3))) void*)l, 16, 0, 0);
}

// ---------------- embedding: h = emb[x]+pos (f32) and bf16 shadow hb ----------------
__global__ __launch_bounds__(256) void k_embed(const int* __restrict__ x,
        const float* __restrict__ emb, const float* __restrict__ pos,
        float* __restrict__ h, bf16* __restrict__ hb) {
    int idx = blockIdx.x*256 + threadIdx.x;     // NTOK*128
    int d   = (idx & 127) * 4;
    int tok = idx >> 7;
    int s   = tok & (SEQ-1);
    int v   = x[tok];
    float4 e4 = *(const float4*)(emb + (size_t)v*D_MODEL + d);
    float4 p4 = *(const float4*)(pos + (size_t)s*D_MODEL + d);
    float4 r; r.x=e4.x+p4.x; r.y=e4.y+p4.y; r.z=e4.z+p4.z; r.w=e4.w+p4.w;
    *(float4*)(h + (size_t)tok*D_MODEL + d) = r;
    bf16 o[4] = { f2b(r.x), f2b(r.y), f2b(r.z), f2b(r.w) };
    *(uint2*)(hb + (size_t)tok*D_MODEL + d) = *(uint2*)&o[0];
}

// ---------------- weight convert f32 -> bf16, zero-padded rows ----------------
__global__ __launch_bounds__(256) void k_cvtw(const float* __restrict__ src,
        bf16* __restrict__ dst, int R, int Kc, int total8) {
    int idx = blockIdx.x*256 + threadIdx.x;
    if (idx >= total8) return;
    int e0 = idx*8;
    int r = e0 / Kc, c = e0 % Kc;
    bf16 tb[8];
    if (r < R) {
        float4 f0 = *(const float4*)(src + (size_t)r*Kc + c);
        float4 f1 = *(const float4*)(src + (size_t)r*Kc + c + 4);
        tb[0]=f2b(f0.x); tb[1]=f2b(f0.y); tb[2]=f2b(f0.z); tb[3]=f2b(f0.w);
        tb[4]=f2b(f1.x); tb[5]=f2b(f1.y); tb[6]=f2b(f1.z); tb[7]=f2b(f1.w);
    } else {
        #pragma unroll
        for (int e=0;e<8;e++) tb[e] = f2b(0.f);
    }
    *(uint4*)(dst + (size_t)r*Kc + c) = *(uint4*)&tb[0];
}

// ---------------- in_proj GEMM 256x256, 8 waves, double-buffered pipeline ----------------
// __launch_bounds__(512, 1): 1 block/CU (128 KB LDS) -> 2 waves/SIMD -> 256 reg/wave
// budget. acc[8][4] = 128 AGPR + operands fit WITHOUT scratch spill (round-8 regression
// root cause: default budget capped VGPR at 128 -> ~90 MB/dispatch spill traffic).
__global__ __launch_bounds__(512, 1) void k_gemm256(const bf16* __restrict__ A,
        const bf16* __restrict__ B, bf16* __restrict__ zbuf,
        bf16* __restrict__ xbcc, float* __restrict__ dt, float* __restrict__ cum,
        const float* __restrict__ cw, const float* __restrict__ cb,
        const float* __restrict__ dt_bias, const float* __restrict__ A_log,
        int ctok)
{
    constexpr int KDIM = 512, NT = KDIM/64, NBX = NPAD/256;
    extern __shared__ __align__(16) char lds[];    // 131072: [2][A 32K | B 32K]
    bf16* Cs = (bf16*)lds;                         // epilogue alias [128][264]

    // bijective XCD swizzle (m204)
    const int nwg = gridDim.x;
    const int q = nwg >> 3, r = nwg & 7;
    const int xcd = blockIdx.x & 7, loc = blockIdx.x >> 3;
    const int wg = ((xcd < r) ? xcd*(q+1) : r*(q+1) + (xcd-r)*q) + loc;
    const int m0 = (wg / NBX) * 256;
    const int n0 = (wg % NBX) * 256;

    const int t = threadIdx.x;
    const int wid = t >> 6, lane = t & 63;
    const int lr = lane & 15, lg = lane >> 4;
    const int wm = (wid >> 2)*128, wn = (wid & 3)*64;
    const int srow = wid*32;
    const int sr   = lane >> 3;                    // row-in-chunk 0..7
    const int scol = ((lane & 7) ^ sr) * 8;        // pre-swizzled source slot

    const bf16* Abase = A + (size_t)(m0 + srow + sr)*KDIM + scol;
    const bf16* Bbase = B + (size_t)(n0 + srow + sr)*KDIM + scol;

    f32x4 acc[8][4] = {};
    char* bc = lds;             // compute buffer
    char* bn = lds + 65536;     // staging buffer

    auto STAGE = [&](char* buf, int kk) {
        #pragma unroll
        for (int c = 0; c < 4; c++) {
            gl_lds16(Abase + (size_t)(c*8)*KDIM + kk, buf + (srow + c*8)*128);
            gl_lds16(Bbase + (size_t)(c*8)*KDIM + kk, buf + 32768 + (srow + c*8)*128);
        }
    };

    STAGE(bc, 0);
    asm volatile("s_waitcnt vmcnt(0)" ::: "memory");
    __builtin_amdgcn_s_barrier();

    #pragma unroll
    for (int kt = 0; kt < NT; kt++) {
        if (kt + 1 < NT) STAGE(bn, (kt+1)*64);     // issue-early: lands under MFMA
        #pragma unroll
        for (int ks = 0; ks < 64; ks += 32) {
            bf16x8 a[8], b[4];
            #pragma unroll
            for (int mi=0;mi<8;mi++) {
                int ra = wm + mi*16 + lr;
                a[mi] = *(const bf16x8*)(bc + ra*128 + ((((ks>>3)+lg) ^ (ra&7))<<4));
            }
            #pragma unroll
            for (int ni=0;ni<4;ni++) {
                int rb = wn + ni*16 + lr;
                b[ni] = *(const bf16x8*)(bc + 32768 + rb*128 + ((((ks>>3)+lg) ^ (rb&7))<<4));
            }
            __builtin_amdgcn_s_setprio(1);
            #pragma unroll
            for (int mi=0;mi<8;mi++)
                #pragma unroll
                for (int ni=0;ni<4;ni++)
                    acc[mi][ni] = __builtin_amdgcn_mfma_f32_16x16x32_bf16(a[mi], b[ni], acc[mi][ni], 0,0,0);
            __builtin_amdgcn_s_setprio(0);
        }
        asm volatile("s_waitcnt vmcnt(0)" ::: "memory");
        __builtin_amdgcn_s_barrier();
        char* tb2 = bc; bc = bn; bn = tb2;
    }
    __builtin_amdgcn_sched_barrier(0);

    // ---- epilogue in two 128-row halves (Cs = [128][264] alias over staging LDS) ----
    const int myhalf = wid >> 2;       // wave owns rows [wm, wm+128)
    const int rsub = t >> 5;           // 0..15
    const int c8   = (t & 31) * 8;     // 0..248, constant per thread

    for (int hp = 0; hp < 2; hp++) {
        __syncthreads();               // Cs region free / prev half's readers done
        if (myhalf == hp) {
            #pragma unroll
            for (int mi=0;mi<8;mi++)
                #pragma unroll
                for (int ni=0;ni<4;ni++)
                    #pragma unroll
                    for (int rr=0;rr<4;rr++)
                        Cs[(mi*16+lg*4+rr)*264 + wn+ni*16+lr] = f2b(acc[mi][ni][rr]);
        }
        __syncthreads();
        const int R0 = hp*128;

        if (n0 < 1024) {
            #pragma unroll
            for (int it = 0; it < 8; it++) {
                int row = it*16 + rsub;
                *(uint4*)(zbuf + (size_t)(m0+R0+row)*1024 + n0 + c8) = *(const uint4*)&Cs[row*264 + c8];
            }
        } else if (n0 < 2304) {
            const int cbase = n0 - 1024 + c8;
            float4 wreg[8]; float bias[8];
            #pragma unroll
            for (int e=0;e<8;e++) wreg[e] = *(const float4*)(cw + (size_t)(cbase+e)*4);
            {
                float4 b0 = *(const float4*)(cb + cbase);
                float4 b1 = *(const float4*)(cb + cbase + 4);
                bias[0]=b0.x; bias[1]=b0.y; bias[2]=b0.z; bias[3]=b0.w;
                bias[4]=b1.x; bias[5]=b1.y; bias[6]=b1.z; bias[7]=b1.w;
            }
            #pragma unroll
            for (int it = 0; it < 8; it++) {
                int row = it*16 + rsub;
                int sl  = row & (SEQ-1);
                float m3 = (sl >= 3) ? 1.f : 0.f;
                float m2 = (sl >= 2) ? 1.f : 0.f;
                float m1 = (sl >= 1) ? 1.f : 0.f;
                const bf16* sm3 = &Cs[(row-3)*264 + c8];
                const bf16* sm2 = &Cs[(row-2)*264 + c8];
                const bf16* sm1 = &Cs[(row-1)*264 + c8];
                const bf16* sm0 = &Cs[(row  )*264 + c8];
                float a[8];
                #pragma unroll
                for (int e=0;e<8;e++) {
                    a[e] = bias[e]
                         + m3 * b2f(sm3[e]) * wreg[e].x
                         + m2 * b2f(sm2[e]) * wreg[e].y
                         + m1 * b2f(sm1[e]) * wreg[e].z
                         +      b2f(sm0[e]) * wreg[e].w;
                }
                bf16 outv[8];
                #pragma unroll
                for (int e=0;e<8;e++) outv[e] = f2b(a[e] / (1.f + __expf(-a[e])));
                *(uint4*)(xbcc + (size_t)(m0+R0+row)*CONV_DIM + cbase) = *(uint4*)&outv[0];
            }
        } else {
            // dt tile (cols 2304-2319): softplus + cumsum per sequence
            for (int p = wid; p < 32; p += 8) {    // (seq-in-half, head)
                int sq = p >> 4, head = p & 15;
                float raw = b2f(Cs[(sq*64 + lane)*264 + head]) + dt_bias[head];
                float dval = (raw > 20.f) ? raw : log1pf(__expf(raw));
                float Ah = -__expf(A_log[head]);
                float cc = dval * Ah;
                #pragma unroll
                for (int o=1;o<64;o<<=1) { float v = __shfl_up(cc, o); if (lane >= o) cc += v; }
                int tok = m0 + R0 + sq*64 + lane;
                dt [(size_t)head*ctok + tok] = dval;
                cum[(size_t)head*ctok + tok] = cc;
            }
        }
    }
}

// ---------------- out_proj GEMM 128x128 (proven 2-phase counted pipeline) ----------------
__global__ __launch_bounds__(256) void k_gemm128(const bf16* __restrict__ A,
        const bf16* __restrict__ B, bf16* __restrict__ C, int Nout, int nbx)
{
    constexpr int KDIM = 1024, NT = KDIM/64;
    __shared__ __align__(16) char lds[65536];
    bf16* Cs = (bf16*)lds;

    const int nwg = gridDim.x;
    const int q = nwg >> 3, r = nwg & 7;
    const int xcd = blockIdx.x & 7, loc = blockIdx.x >> 3;
    const int wg = ((xcd < r) ? xcd*(q+1) : r*(q+1) + (xcd-r)*q) + loc;
    const int m0 = (wg / nbx) * 128;
    const int n0 = (wg % nbx) * 128;

    const int t = threadIdx.x;
    const int wid = t >> 6, lane = t & 63;
    const int lr = lane & 15, lg = lane >> 4;
    const int wm = (wid >> 1)*64, wn = (wid & 1)*64;
    const int srow = wid*32;
    const int sr   = lane >> 3;
    const int scol = ((lane & 7) ^ sr) * 8;

    const bf16* Abase = A + (size_t)(m0 + srow + sr)*KDIM + scol;
    const bf16* Bbase = B + (size_t)(n0 + srow + sr)*KDIM + scol;

    f32x4 acc[4][4] = {};
    char* bc = lds;
    char* bn = lds + 32768;

    auto STAGE = [&](char* buf, int kk) {
        #pragma unroll
        for (int c = 0; c < 4; c++) {
            gl_lds16(Abase + (size_t)(c*8)*KDIM + kk, buf + (srow + c*8)*128);
            gl_lds16(Bbase + (size_t)(c*8)*KDIM + kk, buf + 16384 + (srow + c*8)*128);
        }
    };

    STAGE(bc, 0);
    asm volatile("s_waitcnt vmcnt(0)" ::: "memory");
    __builtin_amdgcn_s_barrier();

    #pragma unroll
    for (int kt = 0; kt < NT; kt++) {
        if (kt + 1 < NT) STAGE(bn, (kt+1)*64);
        #pragma unroll
        for (int ks = 0; ks < 64; ks += 32) {
            bf16x8 a[4], b[4];
            #pragma unroll
            for (int mi=0;mi<4;mi++) {
                int ra = wm + mi*16 + lr;
                a[mi] = *(const bf16x8*)(bc + ra*128 + ((((ks>>3)+lg) ^ (ra&7))<<4));
            }
            #pragma unroll
            for (int ni=0;ni<4;ni++) {
                int rb = wn + ni*16 + lr;
                b[ni] = *(const bf16x8*)(bc + 16384 + rb*128 + ((((ks>>3)+lg) ^ (rb&7))<<4));
            }
            __builtin_amdgcn_s_setprio(1);
            #pragma unroll
            for (int mi=0;mi<4;mi++)
                #pragma unroll
                for (int ni=0;ni<4;ni++)
                    acc[mi][ni] = __builtin_amdgcn_mfma_f32_16x16x32_bf16(a[mi], b[ni], acc[mi][ni], 0,0,0);
            __builtin_amdgcn_s_setprio(0);
        }
        asm volatile("s_waitcnt vmcnt(0)" ::: "memory");
        __builtin_amdgcn_s_barrier();
        char* tb2 = bc; bc = bn; bn = tb2;
    }
    __builtin_amdgcn_sched_barrier(0);

    #pragma unroll
    for (int mi=0;mi<4;mi++)
        #pragma unroll
        for (int ni=0;ni<4;ni++)
            #pragma unroll
            for (int rr=0;rr<4;rr++)
                Cs[(wm+mi*16+lg*4+rr)*136 + wn+ni*16+lr] = f2b(acc[mi][ni][rr]);
    __syncthreads();
    const int rsub = t >> 4;
    const int c8   = (t & 15) * 8;
    #pragma unroll
    for (int it = 0; it < 8; it++) {
        int row = it*16 + rsub;
        *(uint4*)(C + (size_t)(m0+row)*Nout + n0 + c8) = *(const uint4*)&Cs[row*136 + c8];
    }
}

// ---------------- SSD core v2: MFMA for y = W @ xs ----------------
__global__ __launch_bounds__(256) void k_ssd(const bf16* __restrict__ xbcc,
        const float* __restrict__ dt, const float* __restrict__ cum,
        const float* __restrict__ Dskip, bf16* __restrict__ y, int ctok) {
    __shared__ float scores[64][66];
    __shared__ __align__(16) bf16 Wb [64][72];
    __shared__ __align__(16) bf16 xsT[64][72];
    __shared__ __align__(16) bf16 ys [64][72];
    const int bid = blockIdx.x;
    const int b   = bid >> 1;
    const int hg  = (bid & 1) * 8;
    const int t = threadIdx.x;
    const size_t tokbase = (size_t)b*SEQ;
    const int lane = t & 63, lr = lane & 15, lg = lane >> 4;
    const int w = t >> 6;

    {   // scores via MFMA
        int i0 = w*16;
        f32x4 sacc[4] = {};
        const bf16* Cbase = xbcc + tokbase*CONV_DIM + D_INNER + D_STATE;
        const bf16* Bbase = xbcc + tokbase*CONV_DIM + D_INNER;
        #pragma unroll
        for (int ks = 0; ks < D_STATE; ks += 32) {
            bf16x8 af = *(const bf16x8*)(Cbase + (size_t)(i0+lr)*CONV_DIM + ks + lg*8);
            #pragma unroll
            for (int jt = 0; jt < 4; jt++) {
                bf16x8 bfr = *(const bf16x8*)(Bbase + (size_t)(jt*16+lr)*CONV_DIM + ks + lg*8);
                sacc[jt] = __builtin_amdgcn_mfma_f32_16x16x32_bf16(af, bfr, sacc[jt], 0,0,0);
            }
        }
        #pragma unroll
        for (int jt=0;jt<4;jt++)
            #pragma unroll
            for (int rr=0;rr<4;rr++)
                scores[i0 + lg*4 + rr][jt*16 + lr] = sacc[jt][rr];
    }

    const int wi = t >> 2;
    const int wj0 = (t & 3) * 16;

    for (int hl = 0; hl < 8; hl++) {
        const int hh = hg + hl;
        const size_t cbase = (size_t)hh*ctok + tokbase;
        __syncthreads();

        #pragma unroll
        for (int cc = 0; cc < 2; cc++) {
            int ch = cc*256 + t;
            int rr = ch >> 3, c8 = (ch & 7)*8;
            uint4 v = *(const uint4*)(xbcc + (tokbase + rr)*CONV_DIM + hh*HEADDIM + c8);
            const bf16* pv = (const bf16*)&v;
            #pragma unroll
            for (int e=0;e<8;e++) xsT[c8+e][rr] = pv[e];
        }
        {
            float cum_i = cum[cbase + wi];
            float cjf[16], djf[16];
            #pragma unroll
            for (int qq=0; qq<4; qq++) {
                float4 a4 = *(const float4*)(cum + cbase + wj0 + qq*4);
                float4 d4 = *(const float4*)(dt  + cbase + wj0 + qq*4);
                cjf[qq*4+0]=a4.x; cjf[qq*4+1]=a4.y; cjf[qq*4+2]=a4.z; cjf[qq*4+3]=a4.w;
                djf[qq*4+0]=d4.x; djf[qq*4+1]=d4.y; djf[qq*4+2]=d4.z; djf[qq*4+3]=d4.w;
            }
            bf16 tb[16];
            #pragma unroll
            for (int e=0;e<16;e++) {
                int j = wj0 + e;
                float wv = (j <= wi) ? scores[wi][j] * __expf(cum_i - cjf[e]) * djf[e] : 0.f;
                tb[e] = f2b(wv);
            }
            *(uint4*)&Wb[wi][wj0]   = *(uint4*)&tb[0];
            *(uint4*)&Wb[wi][wj0+8] = *(uint4*)&tb[8];
        }
        __syncthreads();

        {
            float dsk = Dskip[hh];
            f32x4 yacc[4] = {};
            #pragma unroll
            for (int ks = 0; ks < 64; ks += 32) {
                bf16x8 a = *(const bf16x8*)&Wb[w*16 + lr][ks + lg*8];
                #pragma unroll
                for (int n=0; n<4; n++) {
                    bf16x8 bb = *(const bf16x8*)&xsT[n*16 + lr][ks + lg*8];
                    yacc[n] = __builtin_amdgcn_mfma_f32_16x16x32_bf16(a, bb, yacc[n], 0,0,0);
                }
            }
            #pragma unroll
            for (int n=0; n<4; n++)
                #pragma unroll
                for (int rr=0; rr<4; rr++) {
                    int row = w*16 + lg*4 + rr;
                    int col = n*16 + lr;
                    ys[row][col] = f2b(yacc[n][rr] + dsk * b2f(xsT[col][row]));
                }
        }
        __syncthreads();

        #pragma unroll
        for (int cc = 0; cc < 2; cc++) {
            int ch = cc*256 + t;
            int rr = ch >> 3, c8 = (ch & 7)*8;
            *(uint4*)(y + (tokbase + rr)*D_INNER + hh*HEADDIM + c8) = *(const uint4*)&ys[rr][c8];
        }
    }
}

// ---------------- y = y*silu(z); RMS-norm * norm_w (2 tokens/block) ----------------
__global__ __launch_bounds__(256) void k_gaterms(bf16* __restrict__ y,
        const bf16* __restrict__ zbuf, const float* __restrict__ nw) {
    int tok = blockIdx.x*2 + (threadIdx.x >> 7);
    int t   = threadIdx.x & 127;
    int hi  = threadIdx.x >> 7, wv = (threadIdx.x >> 6) & 1;
    __shared__ float red[2][2];
    int d = t*8;
    uint4 yv = *(const uint4*)(y    + (size_t)tok*D_INNER + d);
    uint4 zv = *(const uint4*)(zbuf + (size_t)tok*D_INNER + d);
    const unsigned* yu = (const unsigned*)&yv;
    const unsigned* zu = (const unsigned*)&zv;
    float g[8]; float ss = 0.f;
    #pragma unroll
    for (int e=0;e<4;e++) {
        float y0 = bflo(yu[e]), y1 = bfhi(yu[e]);
        float z0 = bflo(zu[e]), z1 = bfhi(zu[e]);
        float g0 = y0 * z0 / (1.f + __expf(-z0));
        float g1 = y1 * z1 / (1.f + __expf(-z1));
        g[2*e] = g0; g[2*e+1] = g1;
        ss += g0*g0 + g1*g1;
    }
    for (int o=32;o>0;o>>=1) ss += __shfl_down(ss, o);
    if ((threadIdx.x & 63) == 0) red[hi][wv] = ss;
    __syncthreads();
    float scale = rsqrtf((red[hi][0]+red[hi][1])/(float)D_INNER + EPS);
    bf16 outv[8];
    #pragma unroll
    for (int e=0;e<8;e++) outv[e] = f2b(g[e] * scale * nw[d+e]);
    *(uint4*)(y + (size_t)tok*D_INNER + d) = *(uint4*)&outv[0];
}

// ---------------- h += layernorm(tmp)*g + b; refresh hb (2 tokens/block) ----------------
__global__ __launch_bounds__(256) void k_resln(float* __restrict__ h,
        bf16* __restrict__ hb, const bf16* __restrict__ tmp,
        const float* __restrict__ g, const float* __restrict__ bb) {
    int tok = blockIdx.x*2 + (threadIdx.x >> 7);
    int t   = threadIdx.x & 127;
    int hi  = threadIdx.x >> 7, wv = (threadIdx.x >> 6) & 1;
    __shared__ float redS[2][2], redQ[2][2];
    int d = t*4;
    uint2 u2 = *(const uint2*)(tmp + (size_t)tok*D_MODEL + d);
    const unsigned* uu = (const unsigned*)&u2;
    float v0 = bflo(uu[0]), v1 = bfhi(uu[0]), v2 = bflo(uu[1]), v3 = bfhi(uu[1]);
    float s = v0+v1+v2+v3;
    float qq = v0*v0+v1*v1+v2*v2+v3*v3;
    for (int o=32;o>0;o>>=1){ s += __shfl_down(s,o); qq += __shfl_down(qq,o); }
    if ((threadIdx.x & 63) == 0){ redS[hi][wv]=s; redQ[hi][wv]=qq; }
    __syncthreads();
    float S = redS[hi][0]+redS[hi][1];
    float Q = redQ[hi][0]+redQ[hi][1];
    float mu  = S/(float)D_MODEL;
    float var = Q/(float)D_MODEL - mu*mu;
    float inv = rsqrtf(var + EPS);
    size_t base = (size_t)tok*D_MODEL + d;
    float4 h4 = *(const float4*)(h + base);
    float4 g4 = *(const float4*)(g + d);
    float4 b4 = *(const float4*)(bb + d);
    h4.x += (v0-mu)*inv*g4.x + b4.x;
    h4.y += (v1-mu)*inv*g4.y + b4.y;
    h4.z += (v2-mu)*inv*g4.z + b4.z;
    h4.w += (v3-mu)*inv*g4.w + b4.w;
    *(float4*)(h + base) = h4;
    bf16 o4[4] = { f2b(h4.x), f2b(h4.y), f2b(h4.z), f2b(h4.w) };
    *(uint2*)(hb + base) = *(uint2*)&o4[0];
}

// ---------------- masked mean-pool over s ----------------
__global__ __launch_bounds__(256) void k_pool(const float* __restrict__ h,
        float* __restrict__ pooled) {
    int b = blockIdx.x, t = threadIdx.x;
    __shared__ float ps[64][4];
    __shared__ float pm[64];
    __shared__ float cntS;
    {
        int s = t >> 2, qq = t & 3;
        const float4* row = (const float4*)(h + ((size_t)b*SEQ + s)*D_MODEL + qq*128);
        float acc = 0;
        #pragma unroll 8
        for (int e=0;e<32;e++) { float4 f = row[e]; acc += f.x+f.y+f.z+f.w; }
        ps[s][qq] = acc;
    }
    __syncthreads();
    if (t < 64) pm[t] = (ps[t][0]+ps[t][1]+ps[t][2]+ps[t][3]) != 0.f ? 1.f : 0.f;
    __syncthreads();
    if (t == 0) { float c=0; for (int s2=0;s2<64;s2++) c+=pm[s2]; cntS = fmaxf(c,1.f); }
    __syncthreads();
    float cnt = cntS;
    #pragma unroll
    for (int rep=0;rep<2;rep++) {
        int d = t + rep*256;
        float acc = 0;
        for (int s2=0;s2<64;s2++) acc += h[((size_t)b*SEQ+s2)*D_MODEL + d] * pm[s2];
        pooled[(size_t)b*D_MODEL + d] = acc / cnt;
    }
}

// ---------------- fc1(relu) + fc2 ----------------
__global__ __launch_bounds__(128) void k_fc(const float* __restrict__ pooled,
        const float* __restrict__ w1, const float* __restrict__ b1,
        const float* __restrict__ w2, const float* __restrict__ b2,
        float* __restrict__ out) {
    int b = blockIdx.x, j = threadIdx.x;
    __shared__ float hid[FC_HID];
    const float* p  = pooled + (size_t)b*D_MODEL;
    const float* wr = w1 + (size_t)j*D_MODEL;
    float acc = b1[j];
    for (int d=0; d<D_MODEL; d+=4)
        acc += p[d]*wr[d] + p[d+1]*wr[d+1] + p[d+2]*wr[d+2] + p[d+3]*wr[d+3];
    hid[j] = fmaxf(acc, 0.f);
    __syncthreads();
    if (j < 2) {
        float o = b2[j];
        for (int k=0;k<FC_HID;k++) o += hid[k]*w2[j*FC_HID+k];
        out[b*2 + j] = o;
    }
}

extern "C" void kernel_launch(void* const* d_in, const int* in_sizes, int n_in,
                              void* d_out, int out_size, void* d_ws, size_t ws_size,
                              hipStream_t stream) {
    (void)in_sizes; (void)n_in; (void)out_size;
    const int*   x        = (const int*)  d_in[0];
    const float* emb      = (const float*)d_in[1];
    const float* pos      = (const float*)d_in[2];
    const float* in_proj  = (const float*)d_in[3];
    const float* conv_w   = (const float*)d_in[4];
    const float* conv_b   = (const float*)d_in[5];
    const float* dt_bias  = (const float*)d_in[6];
    const float* A_log    = (const float*)d_in[7];
    const float* D_skip   = (const float*)d_in[8];
    const float* norm_w   = (const float*)d_in[9];
    const float* out_proj = (const float*)d_in[10];
    const float* ln_g     = (const float*)d_in[11];
    const float* ln_b     = (const float*)d_in[12];
    const float* fc1_w    = (const float*)d_in[13];
    const float* fc1_b    = (const float*)d_in[14];
    const float* fc2_w    = (const float*)d_in[15];
    const float* fc2_b    = (const float*)d_in[16];
    float* out = (float*)d_out;

    // allow 128 KB dynamic LDS for the 256^2 GEMM (idempotent, deterministic)
    (void)hipFuncSetAttribute((const void*)k_gemm256,
            hipFuncAttributeMaxDynamicSharedMemorySize, 131072);

    // ---- persistent region ----
    const size_t H_B   = (size_t)NTOK * D_MODEL * 4;     // 64 MB f32 h
    const size_t HB_B  = (size_t)NTOK * D_MODEL * 2;     // 32 MB bf16 shadow
    const size_t WPI_B = (size_t)NPAD * D_MODEL * 2;     // per layer 2.62 MB
    const size_t WPO_B = (size_t)D_MODEL * D_INNER * 2;  // per layer 1 MB
    const size_t PBASE = H_B + HB_B + NLAYERS*(WPI_B + WPO_B);

    // transients per token: z 2048 + xbcc 2560 + ybuf 2048 + dt/cum 128
    const size_t PER_TOK = 2048 + 2560 + 2048 + 128;     // 6784 B
    int CB = BATCH;
    while (CB > 8 && PBASE + (size_t)CB*SEQ*PER_TOK > ws_size) CB >>= 1;
    const int CT = CB * SEQ;
    const int NC = BATCH / CB;

    char* ws = (char*)d_ws;
    float* h    = (float*)(ws);
    bf16*  hb   = (bf16*) (ws + H_B);
    bf16*  wpi  = (bf16*) (ws + H_B + HB_B);                   // [NLAYERS][NPAD][512]
    bf16*  wpo  = (bf16*) (ws + H_B + HB_B + NLAYERS*WPI_B);   // [NLAYERS][512][1024]
    char*  tr   = ws + PBASE;
    bf16*  zbuf = (bf16*) (tr);                                // CT*1024
    bf16*  xbcc = (bf16*) (tr + (size_t)CT*2048);              // CT*1280
    bf16*  ybuf = (bf16*) (tr + (size_t)CT*(2048+2560));       // CT*1024
    float* dt   = (float*)(tr + (size_t)CT*(2048+2560+2048));  // [16][CT]
    float* cum  = dt + (size_t)CT*NHEADS;
    bf16*  tmp  = xbcc;                 // alias: xbcc dead after k_ssd
    float* pooled = (float*)tr;

    // weight conversion (both layers, once per launch)
    for (int l = 0; l < NLAYERS; l++) {
        int t8i = NPAD*D_MODEL/8;
        k_cvtw<<<(t8i+255)/256, 256, 0, stream>>>(in_proj + (size_t)l*D_IN_PROJ*D_MODEL,
                wpi + (size_t)l*NPAD*D_MODEL, D_IN_PROJ, D_MODEL, t8i);
        int t8o = D_MODEL*D_INNER/8;
        k_cvtw<<<(t8o+255)/256, 256, 0, stream>>>(out_proj + (size_t)l*D_MODEL*D_INNER,
                wpo + (size_t)l*D_MODEL*D_INNER, D_MODEL, D_INNER, t8o);
    }

    k_embed<<<(NTOK*128)/256, 256, 0, stream>>>(x, emb, pos, h, hb);

    const int NBX_O = D_MODEL/128;  // 4

    for (int l = 0; l < NLAYERS; l++) {
        const bf16* wi = wpi + (size_t)l*NPAD*D_MODEL;
        const bf16* wo = wpo + (size_t)l*D_MODEL*D_INNER;
        for (int c = 0; c < NC; c++) {
            const int tok0 = c * CT;
            float* hc  = h  + (size_t)tok0 * D_MODEL;
            bf16*  hbc = hb + (size_t)tok0 * D_MODEL;
            k_gemm256<<<(CT/256)*(NPAD/256), 512, 131072, stream>>>(hbc, wi, zbuf,
                    xbcc, dt, cum,
                    conv_w + (size_t)l*CONV_DIM*D_CONV, conv_b + (size_t)l*CONV_DIM,
                    dt_bias + l*NHEADS, A_log + l*NHEADS, CT);
            k_ssd<<<CB*2, 256, 0, stream>>>(xbcc, dt, cum, D_skip + l*NHEADS, ybuf, CT);
            k_gaterms<<<CT/2, 256, 0, stream>>>(ybuf, zbuf, norm_w + (size_t)l*D_INNER);
            k_gemm128<<<(CT/128)*NBX_O, 256, 0, stream>>>(ybuf, wo, tmp, D_MODEL, NBX_O);
            k_resln<<<CT/2, 256, 0, stream>>>(hc, hbc, tmp, ln_g + l*D_MODEL, ln_b + l*D_MODEL);
        }
    }

    k_pool<<<BATCH, 256, 0, stream>>>(h, pooled);
    k_fc<<<BATCH, FC_HID, 0, stream>>>(pooled, fc1_w, fc1_b, fc2_w, fc2_b, out);
}

// Round 10
// 670.473 us; speedup vs baseline: 1.2133x; 1.2133x over previous
//
#include <hip/hip_runtime.h>
#include <hip/hip_bf16.h>

// ---- problem constants ----
#define D_MODEL   512
#define D_STATE   128
#define D_CONV    4
#define HEADDIM   64
#define NLAYERS   2
#define D_INNER   1024
#define NHEADS    16
#define CONV_DIM  1280          // D_INNER + 2*D_STATE
#define D_IN_PROJ 2320          // 2*D_INNER + 2*D_STATE + NHEADS
#define NPAD      2560          // D_IN_PROJ padded to 256
#define SEQ       64
#define BATCH     512
#define NTOK      (BATCH*SEQ)   // 32768
#define FC_HID    128
#define EPS       1e-5f

using bf16 = __hip_bfloat16;
typedef __bf16 bf16x8 __attribute__((ext_vector_type(8)));
typedef float  f32x4  __attribute__((ext_vector_type(4)));

__device__ __forceinline__ float b2f(bf16 v)  { return __bfloat162float(v); }
__device__ __forceinline__ bf16  f2b(float v) { return __float2bfloat16(v); }
__device__ __forceinline__ float bflo(unsigned u){ return __builtin_bit_cast(float, u << 16); }
__device__ __forceinline__ float bfhi(unsigned u){ return __builtin_bit_cast(float, u & 0xffff0000u); }

__device__ __forceinline__ void gl_lds16(const void* g, void* l) {
    __builtin_amdgcn_global_load_lds((const __attribute__((address_space(1))) void*)g,
                                     (__attribute__((address_space(3))) void*)l, 16, 0, 0);
}

// ---------------- embedding: h = emb[x]+pos (f32) and bf16 shadow hb ----------------
__global__ __launch_bounds__(256) void k_embed(const int* __restrict__ x,
        const float* __restrict__ emb, const float* __restrict__ pos,
        float* __restrict__ h, bf16* __restrict__ hb) {
    int idx = blockIdx.x*256 + threadIdx.x;     // NTOK*128
    int d   = (idx & 127) * 4;
    int tok = idx >> 7;
    int s   = tok & (SEQ-1);
    int v   = x[tok];
    float4 e4 = *(const float4*)(emb + (size_t)v*D_MODEL + d);
    float4 p4 = *(const float4*)(pos + (size_t)s*D_MODEL + d);
    float4 r; r.x=e4.x+p4.x; r.y=e4.y+p4.y; r.z=e4.z+p4.z; r.w=e4.w+p4.w;
    *(float4*)(h + (size_t)tok*D_MODEL + d) = r;
    bf16 o[4] = { f2b(r.x), f2b(r.y), f2b(r.z), f2b(r.w) };
    *(uint2*)(hb + (size_t)tok*D_MODEL + d) = *(uint2*)&o[0];
}

// ---------------- weight convert f32 -> bf16, zero-padded rows ----------------
__global__ __launch_bounds__(256) void k_cvtw(const float* __restrict__ src,
        bf16* __restrict__ dst, int R, int Kc, int total8) {
    int idx = blockIdx.x*256 + threadIdx.x;
    if (idx >= total8) return;
    int e0 = idx*8;
    int r = e0 / Kc, c = e0 % Kc;
    bf16 tb[8];
    if (r < R) {
        float4 f0 = *(const float4*)(src + (size_t)r*Kc + c);
        float4 f1 = *(const float4*)(src + (size_t)r*Kc + c + 4);
        tb[0]=f2b(f0.x); tb[1]=f2b(f0.y); tb[2]=f2b(f0.z); tb[3]=f2b(f0.w);
        tb[4]=f2b(f1.x); tb[5]=f2b(f1.y); tb[6]=f2b(f1.z); tb[7]=f2b(f1.w);
    } else {
        #pragma unroll
        for (int e=0;e<8;e++) tb[e] = f2b(0.f);
    }
    *(uint4*)(dst + (size_t)r*Kc + c) = *(uint4*)&tb[0];
}

// ---------------- in_proj GEMM 256x256, 8 waves, double-buffered pipeline ----------------
// Round-9 fix: acc liveness ends IMMEDIATELY after the K-loop. All waves dump acc
// into a full [256][256] bf16 Cs (exactly 131072 B = the dead staging LDS), with
// row-XOR swizzle (col ^= (row&7)<<3, same involution on write+read). The epilogue
// then runs with zero acc state -> no cross-barrier register liveness -> no spill
// (rounds 8/9 spilled acc of half-1 waves across half-0's epilogue: +94 MB W/+62 MB R).
__global__ __launch_bounds__(512, 1) void k_gemm256(const bf16* __restrict__ A,
        const bf16* __restrict__ B, bf16* __restrict__ zbuf,
        bf16* __restrict__ xbcc, float* __restrict__ dt, float* __restrict__ cum,
        const float* __restrict__ cw, const float* __restrict__ cb,
        const float* __restrict__ dt_bias, const float* __restrict__ A_log,
        int ctok)
{
    constexpr int KDIM = 512, NT = KDIM/64, NBX = NPAD/256;
    extern __shared__ __align__(16) char lds[];    // 131072: [2][A 32K | B 32K]
    bf16* Cs = (bf16*)lds;                         // epilogue alias [256][256] swizzled

    // bijective XCD swizzle (m204)
    const int nwg = gridDim.x;
    const int q = nwg >> 3, r = nwg & 7;
    const int xcd = blockIdx.x & 7, loc = blockIdx.x >> 3;
    const int wg = ((xcd < r) ? xcd*(q+1) : r*(q+1) + (xcd-r)*q) + loc;
    const int m0 = (wg / NBX) * 256;
    const int n0 = (wg % NBX) * 256;

    const int t = threadIdx.x;
    const int wid = t >> 6, lane = t & 63;
    const int lr = lane & 15, lg = lane >> 4;
    const int wm = (wid >> 2)*128, wn = (wid & 3)*64;
    const int srow = wid*32;
    const int sr   = lane >> 3;                    // row-in-chunk 0..7
    const int scol = ((lane & 7) ^ sr) * 8;        // pre-swizzled source slot

    const bf16* Abase = A + (size_t)(m0 + srow + sr)*KDIM + scol;
    const bf16* Bbase = B + (size_t)(n0 + srow + sr)*KDIM + scol;

    f32x4 acc[8][4] = {};
    char* bc = lds;             // compute buffer
    char* bn = lds + 65536;     // staging buffer

    auto STAGE = [&](char* buf, int kk) {
        #pragma unroll
        for (int c = 0; c < 4; c++) {
            gl_lds16(Abase + (size_t)(c*8)*KDIM + kk, buf + (srow + c*8)*128);
            gl_lds16(Bbase + (size_t)(c*8)*KDIM + kk, buf + 32768 + (srow + c*8)*128);
        }
    };

    STAGE(bc, 0);
    asm volatile("s_waitcnt vmcnt(0)" ::: "memory");
    __builtin_amdgcn_s_barrier();

    #pragma unroll
    for (int kt = 0; kt < NT; kt++) {
        if (kt + 1 < NT) STAGE(bn, (kt+1)*64);     // issue-early: lands under MFMA
        #pragma unroll
        for (int ks = 0; ks < 64; ks += 32) {
            bf16x8 a[8], b[4];
            #pragma unroll
            for (int mi=0;mi<8;mi++) {
                int ra = wm + mi*16 + lr;
                a[mi] = *(const bf16x8*)(bc + ra*128 + ((((ks>>3)+lg) ^ (ra&7))<<4));
            }
            #pragma unroll
            for (int ni=0;ni<4;ni++) {
                int rb = wn + ni*16 + lr;
                b[ni] = *(const bf16x8*)(bc + 32768 + rb*128 + ((((ks>>3)+lg) ^ (rb&7))<<4));
            }
            __builtin_amdgcn_s_setprio(1);
            #pragma unroll
            for (int mi=0;mi<8;mi++)
                #pragma unroll
                for (int ni=0;ni<4;ni++)
                    acc[mi][ni] = __builtin_amdgcn_mfma_f32_16x16x32_bf16(a[mi], b[ni], acc[mi][ni], 0,0,0);
            __builtin_amdgcn_s_setprio(0);
        }
        asm volatile("s_waitcnt vmcnt(0)" ::: "memory");
        __builtin_amdgcn_s_barrier();
        char* tb2 = bc; bc = bn; bn = tb2;
    }
    __builtin_amdgcn_sched_barrier(0);
    __syncthreads();    // staging buffers dead; Cs[256][256] alias becomes valid

    // ---- immediate full-tile dump: acc -> Cs (row-XOR swizzle), acc dies here ----
    #pragma unroll
    for (int mi=0;mi<8;mi++)
        #pragma unroll
        for (int ni=0;ni<4;ni++)
            #pragma unroll
            for (int rr=0;rr<4;rr++) {
                int row = wm + mi*16 + lg*4 + rr;
                int col = (wn + ni*16 + lr) ^ ((row & 7) << 3);
                Cs[row*256 + col] = f2b(acc[mi][ni][rr]);
            }
    __syncthreads();

    // ---- unified store phase over all 256 rows (no live acc) ----
    const int rsub = t >> 5;           // 0..15
    const int c8   = (t & 31) * 8;     // 0..248, constant per thread

    if (n0 < 1024) {
        #pragma unroll
        for (int it = 0; it < 16; it++) {
            int row = it*16 + rsub;
            const bf16* src = &Cs[row*256 + (c8 ^ ((row & 7) << 3))];
            *(uint4*)(zbuf + (size_t)(m0+row)*1024 + n0 + c8) = *(const uint4*)src;
        }
    } else if (n0 < 2304) {
        const int cbase = n0 - 1024 + c8;
        float4 wreg[8]; float bias[8];
        #pragma unroll
        for (int e=0;e<8;e++) wreg[e] = *(const float4*)(cw + (size_t)(cbase+e)*4);
        {
            float4 b0 = *(const float4*)(cb + cbase);
            float4 b1 = *(const float4*)(cb + cbase + 4);
            bias[0]=b0.x; bias[1]=b0.y; bias[2]=b0.z; bias[3]=b0.w;
            bias[4]=b1.x; bias[5]=b1.y; bias[6]=b1.z; bias[7]=b1.w;
        }
        #pragma unroll
        for (int it = 0; it < 16; it++) {
            int row = it*16 + rsub;
            int sl  = row & (SEQ-1);
            float m3 = (sl >= 3) ? 1.f : 0.f;
            float m2 = (sl >= 2) ? 1.f : 0.f;
            float m1 = (sl >= 1) ? 1.f : 0.f;
            const bf16* sm3 = &Cs[(row-3)*256 + (c8 ^ (((row-3) & 7) << 3))];
            const bf16* sm2 = &Cs[(row-2)*256 + (c8 ^ (((row-2) & 7) << 3))];
            const bf16* sm1 = &Cs[(row-1)*256 + (c8 ^ (((row-1) & 7) << 3))];
            const bf16* sm0 = &Cs[(row  )*256 + (c8 ^ (((row  ) & 7) << 3))];
            float a[8];
            #pragma unroll
            for (int e=0;e<8;e++) {
                a[e] = bias[e]
                     + m3 * b2f(sm3[e]) * wreg[e].x
                     + m2 * b2f(sm2[e]) * wreg[e].y
                     + m1 * b2f(sm1[e]) * wreg[e].z
                     +      b2f(sm0[e]) * wreg[e].w;
            }
            bf16 outv[8];
            #pragma unroll
            for (int e=0;e<8;e++) outv[e] = f2b(a[e] / (1.f + __expf(-a[e])));
            *(uint4*)(xbcc + (size_t)(m0+row)*CONV_DIM + cbase) = *(uint4*)&outv[0];
        }
    } else {
        // dt tile (cols 2304-2319 -> local 0-15): softplus + cumsum per sequence
        for (int p = wid; p < 64; p += 8) {        // (seq-in-tile 0..3, head 0..15)
            int sq = p >> 4, head = p & 15;
            int row = sq*64 + lane;
            float raw = b2f(Cs[row*256 + (head ^ ((row & 7) << 3))]) + dt_bias[head];
            float dval = (raw > 20.f) ? raw : log1pf(__expf(raw));
            float Ah = -__expf(A_log[head]);
            float cc = dval * Ah;
            #pragma unroll
            for (int o=1;o<64;o<<=1) { float v = __shfl_up(cc, o); if (lane >= o) cc += v; }
            int tok = m0 + row;
            dt [(size_t)head*ctok + tok] = dval;
            cum[(size_t)head*ctok + tok] = cc;
        }
    }
}

// ---------------- out_proj GEMM 128x128 (proven 2-phase counted pipeline) ----------------
__global__ __launch_bounds__(256) void k_gemm128(const bf16* __restrict__ A,
        const bf16* __restrict__ B, bf16* __restrict__ C, int Nout, int nbx)
{
    constexpr int KDIM = 1024, NT = KDIM/64;
    __shared__ __align__(16) char lds[65536];
    bf16* Cs = (bf16*)lds;

    const int nwg = gridDim.x;
    const int q = nwg >> 3, r = nwg & 7;
    const int xcd = blockIdx.x & 7, loc = blockIdx.x >> 3;
    const int wg = ((xcd < r) ? xcd*(q+1) : r*(q+1) + (xcd-r)*q) + loc;
    const int m0 = (wg / nbx) * 128;
    const int n0 = (wg % nbx) * 128;

    const int t = threadIdx.x;
    const int wid = t >> 6, lane = t & 63;
    const int lr = lane & 15, lg = lane >> 4;
    const int wm = (wid >> 1)*64, wn = (wid & 1)*64;
    const int srow = wid*32;
    const int sr   = lane >> 3;
    const int scol = ((lane & 7) ^ sr) * 8;

    const bf16* Abase = A + (size_t)(m0 + srow + sr)*KDIM + scol;
    const bf16* Bbase = B + (size_t)(n0 + srow + sr)*KDIM + scol;

    f32x4 acc[4][4] = {};
    char* bc = lds;
    char* bn = lds + 32768;

    auto STAGE = [&](char* buf, int kk) {
        #pragma unroll
        for (int c = 0; c < 4; c++) {
            gl_lds16(Abase + (size_t)(c*8)*KDIM + kk, buf + (srow + c*8)*128);
            gl_lds16(Bbase + (size_t)(c*8)*KDIM + kk, buf + 16384 + (srow + c*8)*128);
        }
    };

    STAGE(bc, 0);
    asm volatile("s_waitcnt vmcnt(0)" ::: "memory");
    __builtin_amdgcn_s_barrier();

    #pragma unroll
    for (int kt = 0; kt < NT; kt++) {
        if (kt + 1 < NT) STAGE(bn, (kt+1)*64);
        #pragma unroll
        for (int ks = 0; ks < 64; ks += 32) {
            bf16x8 a[4], b[4];
            #pragma unroll
            for (int mi=0;mi<4;mi++) {
                int ra = wm + mi*16 + lr;
                a[mi] = *(const bf16x8*)(bc + ra*128 + ((((ks>>3)+lg) ^ (ra&7))<<4));
            }
            #pragma unroll
            for (int ni=0;ni<4;ni++) {
                int rb = wn + ni*16 + lr;
                b[ni] = *(const bf16x8*)(bc + 16384 + rb*128 + ((((ks>>3)+lg) ^ (rb&7))<<4));
            }
            __builtin_amdgcn_s_setprio(1);
            #pragma unroll
            for (int mi=0;mi<4;mi++)
                #pragma unroll
                for (int ni=0;ni<4;ni++)
                    acc[mi][ni] = __builtin_amdgcn_mfma_f32_16x16x32_bf16(a[mi], b[ni], acc[mi][ni], 0,0,0);
            __builtin_amdgcn_s_setprio(0);
        }
        asm volatile("s_waitcnt vmcnt(0)" ::: "memory");
        __builtin_amdgcn_s_barrier();
        char* tb2 = bc; bc = bn; bn = tb2;
    }
    __builtin_amdgcn_sched_barrier(0);

    #pragma unroll
    for (int mi=0;mi<4;mi++)
        #pragma unroll
        for (int ni=0;ni<4;ni++)
            #pragma unroll
            for (int rr=0;rr<4;rr++)
                Cs[(wm+mi*16+lg*4+rr)*136 + wn+ni*16+lr] = f2b(acc[mi][ni][rr]);
    __syncthreads();
    const int rsub = t >> 4;
    const int c8   = (t & 15) * 8;
    #pragma unroll
    for (int it = 0; it < 8; it++) {
        int row = it*16 + rsub;
        *(uint4*)(C + (size_t)(m0+row)*Nout + n0 + c8) = *(const uint4*)&Cs[row*136 + c8];
    }
}

// ---------------- SSD core v2: MFMA for y = W @ xs ----------------
__global__ __launch_bounds__(256) void k_ssd(const bf16* __restrict__ xbcc,
        const float* __restrict__ dt, const float* __restrict__ cum,
        const float* __restrict__ Dskip, bf16* __restrict__ y, int ctok) {
    __shared__ float scores[64][66];
    __shared__ __align__(16) bf16 Wb [64][72];
    __shared__ __align__(16) bf16 xsT[64][72];
    __shared__ __align__(16) bf16 ys [64][72];
    const int bid = blockIdx.x;
    const int b   = bid >> 1;
    const int hg  = (bid & 1) * 8;
    const int t = threadIdx.x;
    const size_t tokbase = (size_t)b*SEQ;
    const int lane = t & 63, lr = lane & 15, lg = lane >> 4;
    const int w = t >> 6;

    {   // scores via MFMA
        int i0 = w*16;
        f32x4 sacc[4] = {};
        const bf16* Cbase = xbcc + tokbase*CONV_DIM + D_INNER + D_STATE;
        const bf16* Bbase = xbcc + tokbase*CONV_DIM + D_INNER;
        #pragma unroll
        for (int ks = 0; ks < D_STATE; ks += 32) {
            bf16x8 af = *(const bf16x8*)(Cbase + (size_t)(i0+lr)*CONV_DIM + ks + lg*8);
            #pragma unroll
            for (int jt = 0; jt < 4; jt++) {
                bf16x8 bfr = *(const bf16x8*)(Bbase + (size_t)(jt*16+lr)*CONV_DIM + ks + lg*8);
                sacc[jt] = __builtin_amdgcn_mfma_f32_16x16x32_bf16(af, bfr, sacc[jt], 0,0,0);
            }
        }
        #pragma unroll
        for (int jt=0;jt<4;jt++)
            #pragma unroll
            for (int rr=0;rr<4;rr++)
                scores[i0 + lg*4 + rr][jt*16 + lr] = sacc[jt][rr];
    }

    const int wi = t >> 2;
    const int wj0 = (t & 3) * 16;

    for (int hl = 0; hl < 8; hl++) {
        const int hh = hg + hl;
        const size_t cbase = (size_t)hh*ctok + tokbase;
        __syncthreads();

        #pragma unroll
        for (int cc = 0; cc < 2; cc++) {
            int ch = cc*256 + t;
            int rr = ch >> 3, c8 = (ch & 7)*8;
            uint4 v = *(const uint4*)(xbcc + (tokbase + rr)*CONV_DIM + hh*HEADDIM + c8);
            const bf16* pv = (const bf16*)&v;
            #pragma unroll
            for (int e=0;e<8;e++) xsT[c8+e][rr] = pv[e];
        }
        {
            float cum_i = cum[cbase + wi];
            float cjf[16], djf[16];
            #pragma unroll
            for (int qq=0; qq<4; qq++) {
                float4 a4 = *(const float4*)(cum + cbase + wj0 + qq*4);
                float4 d4 = *(const float4*)(dt  + cbase + wj0 + qq*4);
                cjf[qq*4+0]=a4.x; cjf[qq*4+1]=a4.y; cjf[qq*4+2]=a4.z; cjf[qq*4+3]=a4.w;
                djf[qq*4+0]=d4.x; djf[qq*4+1]=d4.y; djf[qq*4+2]=d4.z; djf[qq*4+3]=d4.w;
            }
            bf16 tb[16];
            #pragma unroll
            for (int e=0;e<16;e++) {
                int j = wj0 + e;
                float wv = (j <= wi) ? scores[wi][j] * __expf(cum_i - cjf[e]) * djf[e] : 0.f;
                tb[e] = f2b(wv);
            }
            *(uint4*)&Wb[wi][wj0]   = *(uint4*)&tb[0];
            *(uint4*)&Wb[wi][wj0+8] = *(uint4*)&tb[8];
        }
        __syncthreads();

        {
            float dsk = Dskip[hh];
            f32x4 yacc[4] = {};
            #pragma unroll
            for (int ks = 0; ks < 64; ks += 32) {
                bf16x8 a = *(const bf16x8*)&Wb[w*16 + lr][ks + lg*8];
                #pragma unroll
                for (int n=0; n<4; n++) {
                    bf16x8 bb = *(const bf16x8*)&xsT[n*16 + lr][ks + lg*8];
                    yacc[n] = __builtin_amdgcn_mfma_f32_16x16x32_bf16(a, bb, yacc[n], 0,0,0);
                }
            }
            #pragma unroll
            for (int n=0; n<4; n++)
                #pragma unroll
                for (int rr=0; rr<4; rr++) {
                    int row = w*16 + lg*4 + rr;
                    int col = n*16 + lr;
                    ys[row][col] = f2b(yacc[n][rr] + dsk * b2f(xsT[col][row]));
                }
        }
        __syncthreads();

        #pragma unroll
        for (int cc = 0; cc < 2; cc++) {
            int ch = cc*256 + t;
            int rr = ch >> 3, c8 = (ch & 7)*8;
            *(uint4*)(y + (tokbase + rr)*D_INNER + hh*HEADDIM + c8) = *(const uint4*)&ys[rr][c8];
        }
    }
}

// ---------------- y = y*silu(z); RMS-norm * norm_w (2 tokens/block) ----------------
__global__ __launch_bounds__(256) void k_gaterms(bf16* __restrict__ y,
        const bf16* __restrict__ zbuf, const float* __restrict__ nw) {
    int tok = blockIdx.x*2 + (threadIdx.x >> 7);
    int t   = threadIdx.x & 127;
    int hi  = threadIdx.x >> 7, wv = (threadIdx.x >> 6) & 1;
    __shared__ float red[2][2];
    int d = t*8;
    uint4 yv = *(const uint4*)(y    + (size_t)tok*D_INNER + d);
    uint4 zv = *(const uint4*)(zbuf + (size_t)tok*D_INNER + d);
    const unsigned* yu = (const unsigned*)&yv;
    const unsigned* zu = (const unsigned*)&zv;
    float g[8]; float ss = 0.f;
    #pragma unroll
    for (int e=0;e<4;e++) {
        float y0 = bflo(yu[e]), y1 = bfhi(yu[e]);
        float z0 = bflo(zu[e]), z1 = bfhi(zu[e]);
        float g0 = y0 * z0 / (1.f + __expf(-z0));
        float g1 = y1 * z1 / (1.f + __expf(-z1));
        g[2*e] = g0; g[2*e+1] = g1;
        ss += g0*g0 + g1*g1;
    }
    for (int o=32;o>0;o>>=1) ss += __shfl_down(ss, o);
    if ((threadIdx.x & 63) == 0) red[hi][wv] = ss;
    __syncthreads();
    float scale = rsqrtf((red[hi][0]+red[hi][1])/(float)D_INNER + EPS);
    bf16 outv[8];
    #pragma unroll
    for (int e=0;e<8;e++) outv[e] = f2b(g[e] * scale * nw[d+e]);
    *(uint4*)(y + (size_t)tok*D_INNER + d) = *(uint4*)&outv[0];
}

// ---------------- h += layernorm(tmp)*g + b; refresh hb (2 tokens/block) ----------------
__global__ __launch_bounds__(256) void k_resln(float* __restrict__ h,
        bf16* __restrict__ hb, const bf16* __restrict__ tmp,
        const float* __restrict__ g, const float* __restrict__ bb) {
    int tok = blockIdx.x*2 + (threadIdx.x >> 7);
    int t   = threadIdx.x & 127;
    int hi  = threadIdx.x >> 7, wv = (threadIdx.x >> 6) & 1;
    __shared__ float redS[2][2], redQ[2][2];
    int d = t*4;
    uint2 u2 = *(const uint2*)(tmp + (size_t)tok*D_MODEL + d);
    const unsigned* uu = (const unsigned*)&u2;
    float v0 = bflo(uu[0]), v1 = bfhi(uu[0]), v2 = bflo(uu[1]), v3 = bfhi(uu[1]);
    float s = v0+v1+v2+v3;
    float qq = v0*v0+v1*v1+v2*v2+v3*v3;
    for (int o=32;o>0;o>>=1){ s += __shfl_down(s,o); qq += __shfl_down(qq,o); }
    if ((threadIdx.x & 63) == 0){ redS[hi][wv]=s; redQ[hi][wv]=qq; }
    __syncthreads();
    float S = redS[hi][0]+redS[hi][1];
    float Q = redQ[hi][0]+redQ[hi][1];
    float mu  = S/(float)D_MODEL;
    float var = Q/(float)D_MODEL - mu*mu;
    float inv = rsqrtf(var + EPS);
    size_t base = (size_t)tok*D_MODEL + d;
    float4 h4 = *(const float4*)(h + base);
    float4 g4 = *(const float4*)(g + d);
    float4 b4 = *(const float4*)(bb + d);
    h4.x += (v0-mu)*inv*g4.x + b4.x;
    h4.y += (v1-mu)*inv*g4.y + b4.y;
    h4.z += (v2-mu)*inv*g4.z + b4.z;
    h4.w += (v3-mu)*inv*g4.w + b4.w;
    *(float4*)(h + base) = h4;
    bf16 o4[4] = { f2b(h4.x), f2b(h4.y), f2b(h4.z), f2b(h4.w) };
    *(uint2*)(hb + base) = *(uint2*)&o4[0];
}

// ---------------- masked mean-pool over s ----------------
__global__ __launch_bounds__(256) void k_pool(const float* __restrict__ h,
        float* __restrict__ pooled) {
    int b = blockIdx.x, t = threadIdx.x;
    __shared__ float ps[64][4];
    __shared__ float pm[64];
    __shared__ float cntS;
    {
        int s = t >> 2, qq = t & 3;
        const float4* row = (const float4*)(h + ((size_t)b*SEQ + s)*D_MODEL + qq*128);
        float acc = 0;
        #pragma unroll 8
        for (int e=0;e<32;e++) { float4 f = row[e]; acc += f.x+f.y+f.z+f.w; }
        ps[s][qq] = acc;
    }
    __syncthreads();
    if (t < 64) pm[t] = (ps[t][0]+ps[t][1]+ps[t][2]+ps[t][3]) != 0.f ? 1.f : 0.f;
    __syncthreads();
    if (t == 0) { float c=0; for (int s2=0;s2<64;s2++) c+=pm[s2]; cntS = fmaxf(c,1.f); }
    __syncthreads();
    float cnt = cntS;
    #pragma unroll
    for (int rep=0;rep<2;rep++) {
        int d = t + rep*256;
        float acc = 0;
        for (int s2=0;s2<64;s2++) acc += h[((size_t)b*SEQ+s2)*D_MODEL + d] * pm[s2];
        pooled[(size_t)b*D_MODEL + d] = acc / cnt;
    }
}

// ---------------- fc1(relu) + fc2 ----------------
__global__ __launch_bounds__(128) void k_fc(const float* __restrict__ pooled,
        const float* __restrict__ w1, const float* __restrict__ b1,
        const float* __restrict__ w2, const float* __restrict__ b2,
        float* __restrict__ out) {
    int b = blockIdx.x, j = threadIdx.x;
    __shared__ float hid[FC_HID];
    const float* p  = pooled + (size_t)b*D_MODEL;
    const float* wr = w1 + (size_t)j*D_MODEL;
    float acc = b1[j];
    for (int d=0; d<D_MODEL; d+=4)
        acc += p[d]*wr[d] + p[d+1]*wr[d+1] + p[d+2]*wr[d+2] + p[d+3]*wr[d+3];
    hid[j] = fmaxf(acc, 0.f);
    __syncthreads();
    if (j < 2) {
        float o = b2[j];
        for (int k=0;k<FC_HID;k++) o += hid[k]*w2[j*FC_HID+k];
        out[b*2 + j] = o;
    }
}

extern "C" void kernel_launch(void* const* d_in, const int* in_sizes, int n_in,
                              void* d_out, int out_size, void* d_ws, size_t ws_size,
                              hipStream_t stream) {
    (void)in_sizes; (void)n_in; (void)out_size;
    const int*   x        = (const int*)  d_in[0];
    const float* emb      = (const float*)d_in[1];
    const float* pos      = (const float*)d_in[2];
    const float* in_proj  = (const float*)d_in[3];
    const float* conv_w   = (const float*)d_in[4];
    const float* conv_b   = (const float*)d_in[5];
    const float* dt_bias  = (const float*)d_in[6];
    const float* A_log    = (const float*)d_in[7];
    const float* D_skip   = (const float*)d_in[8];
    const float* norm_w   = (const float*)d_in[9];
    const float* out_proj = (const float*)d_in[10];
    const float* ln_g     = (const float*)d_in[11];
    const float* ln_b     = (const float*)d_in[12];
    const float* fc1_w    = (const float*)d_in[13];
    const float* fc1_b    = (const float*)d_in[14];
    const float* fc2_w    = (const float*)d_in[15];
    const float* fc2_b    = (const float*)d_in[16];
    float* out = (float*)d_out;

    // allow 128 KB dynamic LDS for the 256^2 GEMM (idempotent, deterministic)
    (void)hipFuncSetAttribute((const void*)k_gemm256,
            hipFuncAttributeMaxDynamicSharedMemorySize, 131072);

    // ---- persistent region ----
    const size_t H_B   = (size_t)NTOK * D_MODEL * 4;     // 64 MB f32 h
    const size_t HB_B  = (size_t)NTOK * D_MODEL * 2;     // 32 MB bf16 shadow
    const size_t WPI_B = (size_t)NPAD * D_MODEL * 2;     // per layer 2.62 MB
    const size_t WPO_B = (size_t)D_MODEL * D_INNER * 2;  // per layer 1 MB
    const size_t PBASE = H_B + HB_B + NLAYERS*(WPI_B + WPO_B);

    // transients per token: z 2048 + xbcc 2560 + ybuf 2048 + dt/cum 128
    const size_t PER_TOK = 2048 + 2560 + 2048 + 128;     // 6784 B
    int CB = BATCH;
    while (CB > 8 && PBASE + (size_t)CB*SEQ*PER_TOK > ws_size) CB >>= 1;
    const int CT = CB * SEQ;
    const int NC = BATCH / CB;

    char* ws = (char*)d_ws;
    float* h    = (float*)(ws);
    bf16*  hb   = (bf16*) (ws + H_B);
    bf16*  wpi  = (bf16*) (ws + H_B + HB_B);                   // [NLAYERS][NPAD][512]
    bf16*  wpo  = (bf16*) (ws + H_B + HB_B + NLAYERS*WPI_B);   // [NLAYERS][512][1024]
    char*  tr   = ws + PBASE;
    bf16*  zbuf = (bf16*) (tr);                                // CT*1024
    bf16*  xbcc = (bf16*) (tr + (size_t)CT*2048);              // CT*1280
    bf16*  ybuf = (bf16*) (tr + (size_t)CT*(2048+2560));       // CT*1024
    float* dt   = (float*)(tr + (size_t)CT*(2048+2560+2048));  // [16][CT]
    float* cum  = dt + (size_t)CT*NHEADS;
    bf16*  tmp  = xbcc;                 // alias: xbcc dead after k_ssd
    float* pooled = (float*)tr;

    // weight conversion (both layers, once per launch)
    for (int l = 0; l < NLAYERS; l++) {
        int t8i = NPAD*D_MODEL/8;
        k_cvtw<<<(t8i+255)/256, 256, 0, stream>>>(in_proj + (size_t)l*D_IN_PROJ*D_MODEL,
                wpi + (size_t)l*NPAD*D_MODEL, D_IN_PROJ, D_MODEL, t8i);
        int t8o = D_MODEL*D_INNER/8;
        k_cvtw<<<(t8o+255)/256, 256, 0, stream>>>(out_proj + (size_t)l*D_MODEL*D_INNER,
                wpo + (size_t)l*D_MODEL*D_INNER, D_MODEL, D_INNER, t8o);
    }

    k_embed<<<(NTOK*128)/256, 256, 0, stream>>>(x, emb, pos, h, hb);

    const int NBX_O = D_MODEL/128;  // 4

    for (int l = 0; l < NLAYERS; l++) {
        const bf16* wi = wpi + (size_t)l*NPAD*D_MODEL;
        const bf16* wo = wpo + (size_t)l*D_MODEL*D_INNER;
        for (int c = 0; c < NC; c++) {
            const int tok0 = c * CT;
            float* hc  = h  + (size_t)tok0 * D_MODEL;
            bf16*  hbc = hb + (size_t)tok0 * D_MODEL;
            k_gemm256<<<(CT/256)*(NPAD/256), 512, 131072, stream>>>(hbc, wi, zbuf,
                    xbcc, dt, cum,
                    conv_w + (size_t)l*CONV_DIM*D_CONV, conv_b + (size_t)l*CONV_DIM,
                    dt_bias + l*NHEADS, A_log + l*NHEADS, CT);
            k_ssd<<<CB*2, 256, 0, stream>>>(xbcc, dt, cum, D_skip + l*NHEADS, ybuf, CT);
            k_gaterms<<<CT/2, 256, 0, stream>>>(ybuf, zbuf, norm_w + (size_t)l*D_INNER);
            k_gemm128<<<(CT/128)*NBX_O, 256, 0, stream>>>(ybuf, wo, tmp, D_MODEL, NBX_O);
            k_resln<<<CT/2, 256, 0, stream>>>(hc, hbc, tmp, ln_g + l*D_MODEL, ln_b + l*D_MODEL);
        }
    }

    k_pool<<<BATCH, 256, 0, stream>>>(h, pooled);
    k_fc<<<BATCH, FC_HID, 0, stream>>>(pooled, fc1_w, fc1_b, fc2_w, fc2_b, out);
}